// Round 8
// baseline (591.289 us; speedup 1.0000x reference)
//
#include <hip/hip_runtime.h>
#include <hip/hip_bf16.h>

// SelfAttention: out = softmax(causal((Ez Wq^T)(Ez Wk^T)^T / sqrt(512))) (Ez Wv^T)
// B=32, L=2048, DIM=512. f32 in/out; bf16 MFMA internally.
// ws: Qb (bf16, Q*SCALE*LOG2E), Kb (bf16), Vtb (bf16, [b][t][e][32] tile-contig,
// LINEAR). Wb (bf16 [g][kt][n][32], swizzled) in d_out scratch.

typedef __attribute__((ext_vector_type(8))) short short8;
typedef __attribute__((ext_vector_type(4))) short short4v;
typedef __attribute__((ext_vector_type(4))) float f32x4;

#define DIM 512
#define LSEQ 2048
#define NB 32
#define SCALE 0.04419417382415922f
#define LOG2E 1.4426950408889634f

__device__ __forceinline__ short f2bs(float f) {
  __hip_bfloat16 h = __float2bfloat16(f);
  return __builtin_bit_cast(short, h);
}

__device__ __forceinline__ void gld16(const void* g, void* l) {
  __builtin_amdgcn_global_load_lds(
      (const unsigned int __attribute__((address_space(1)))*)g,
      (unsigned int __attribute__((address_space(3)))*)l, 16, 0, 0);
}

// ---- W[z] f32 -> bf16, layout [g][kt][n][32 d-chunk-swizzled] --------------
__global__ __launch_bounds__(256) void wcvt_kernel(
    const float* __restrict__ Wq, const float* __restrict__ Wk,
    const float* __restrict__ Wv, const int* __restrict__ zp,
    short* __restrict__ Wb) {
  int z = *zp;
  int i = blockIdx.x * 256 + threadIdx.x;
  int g = i >> 15;
  int off = (i & 32767) * 8;                   // flat [n][d], d fast
  int n = off >> 9, d0 = off & 511;
  int kt = d0 >> 5, c = d0 & 31;
  int sw = ((c >> 3) ^ ((n >> 1) & 3));
  const float* src = (g == 0 ? Wq : (g == 1 ? Wk : Wv)) + (size_t)z * DIM * DIM + off;
  float4 a = *(const float4*)src, b = *(const float4*)(src + 4);
  short8 v;
  v[0]=f2bs(a.x); v[1]=f2bs(a.y); v[2]=f2bs(a.z); v[3]=f2bs(a.w);
  v[4]=f2bs(b.x); v[5]=f2bs(b.y); v[6]=f2bs(b.z); v[7]=f2bs(b.w);
  *(short8*)&Wb[((size_t)(g * 16 + kt) * 512 + n) * 32 + sw * 8] = v;
}

// ---- projection GEMM: C[m][n] = sum_d Ez[m][d] * W[n][d] -------------------
__global__ __launch_bounds__(512, 4) void proj_kernel(
    const float* __restrict__ Ez, const short* __restrict__ Wb,
    short* __restrict__ Qb, short* __restrict__ Kb, short* __restrict__ Vtb) {
  int g = blockIdx.z;
  const short* W = Wb + (size_t)g * 16 * 512 * 32;
  __shared__ short As[2][64 * 32];
  __shared__ short Bs[2][512 * 32];
  int tid = threadIdx.x, lane = tid & 63, wid = tid >> 6;
  int l15 = lane & 15, lg = lane >> 4;
  int m0 = blockIdx.x * 64;
  int sw = (l15 >> 1) & 3;
  f32x4 zero4 = {0.f, 0.f, 0.f, 0.f};
  f32x4 acc[4][4];
  #pragma unroll
  for (int mi = 0; mi < 4; mi++)
    #pragma unroll
    for (int ni = 0; ni < 4; ni++) acc[mi][ni] = zero4;

  int arow = tid >> 3, aq = tid & 7;
  int aoff = arow * 32 + (((aq >> 1) ^ ((arow >> 1) & 3)) << 3) + (aq & 1) * 4;
  const float* aptr = Ez + (size_t)(m0 + arow) * DIM + aq * 4;

  {  // prologue: stage kt=0
    float4 a = *(const float4*)aptr;
    short4v av;
    av[0]=f2bs(a.x); av[1]=f2bs(a.y); av[2]=f2bs(a.z); av[3]=f2bs(a.w);
    *(short4v*)&As[0][aoff] = av;
    #pragma unroll
    for (int ii = 0; ii < 4; ii++) {
      int s = wid * 4 + ii;
      gld16(W + s * 512 + lane * 8, &Bs[0][s * 512]);
    }
  }
  __syncthreads();

  #pragma unroll 2
  for (int kt = 0; kt < 16; kt++) {
    int cur = kt & 1;
    float4 a;
    if (kt < 15) {
      a = *(const float4*)(aptr + (kt + 1) * 32);
      #pragma unroll
      for (int ii = 0; ii < 4; ii++) {
        int s = wid * 4 + ii;
        gld16(W + (size_t)(kt + 1) * 16384 + s * 512 + lane * 8, &Bs[cur ^ 1][s * 512]);
      }
    }
    short8 af[4], bf[4];
    #pragma unroll
    for (int mi = 0; mi < 4; mi++)
      af[mi] = *(const short8*)&As[cur][(mi * 16 + l15) * 32 + ((lg ^ sw) << 3)];
    #pragma unroll
    for (int ni = 0; ni < 4; ni++)
      bf[ni] = *(const short8*)&Bs[cur][(wid * 64 + ni * 16 + l15) * 32 + ((lg ^ sw) << 3)];
    __builtin_amdgcn_s_setprio(1);
    #pragma unroll
    for (int mi = 0; mi < 4; mi++)
      #pragma unroll
      for (int ni = 0; ni < 4; ni++)
        acc[mi][ni] = __builtin_amdgcn_mfma_f32_16x16x32_bf16(af[mi], bf[ni], acc[mi][ni], 0, 0, 0);
    __builtin_amdgcn_s_setprio(0);
    if (kt < 15) {
      short4v av;
      av[0]=f2bs(a.x); av[1]=f2bs(a.y); av[2]=f2bs(a.z); av[3]=f2bs(a.w);
      *(short4v*)&As[cur ^ 1][aoff] = av;
    }
    __syncthreads();
  }

  if (g == 2) {
    #pragma unroll
    for (int mi = 0; mi < 4; mi++) {
      int gm0 = m0 + mi * 16 + lg * 4;
      int b = gm0 >> 11, l0 = gm0 & (LSEQ - 1);
      int t = l0 >> 5, c0 = l0 & 31;
      #pragma unroll
      for (int ni = 0; ni < 4; ni++) {
        int e = wid * 64 + ni * 16 + l15;
        short4v v;
        v[0]=f2bs(acc[mi][ni][0]); v[1]=f2bs(acc[mi][ni][1]);
        v[2]=f2bs(acc[mi][ni][2]); v[3]=f2bs(acc[mi][ni][3]);
        size_t idx = ((size_t)(b * 64 + t) * 512 + e) * 32 + c0;  // linear tile
        *(short4v*)&Vtb[idx] = v;
      }
    }
  } else {
    short* dst = (g == 0 ? Qb : Kb);
    float sc = (g == 0 ? SCALE * LOG2E : 1.0f);  // Q pre-scaled, exp2 domain
    #pragma unroll
    for (int mi = 0; mi < 4; mi++) {
      int gm0 = m0 + mi * 16 + lg * 4;
      #pragma unroll
      for (int ni = 0; ni < 4; ni++) {
        int gn = wid * 64 + ni * 16 + l15;
        #pragma unroll
        for (int r = 0; r < 4; r++)
          dst[(size_t)(gm0 + r) * DIM + gn] = f2bs(acc[mi][ni][r] * sc);
      }
    }
  }
}

// ---- flash attention (causal) ----------------------------------------------
// 512 threads, 8 waves. QK^T: wave w owns q-rows [w*16,+16). PV d-split:
// wave w owns out dims [w*64,+64) for all 128 q-rows. P double-buffered in
// LDS -> 1 barrier/tile. V read directly from global (L2-hot, coalesced 1KB,
// issued at tile start, consumed after barrier): V never touches LDS.
__device__ __forceinline__ void stage_k(const short* __restrict__ Kb,
                                        short* Klbuf,
                                        int batch, int t, int wid, int lane) {
  #pragma unroll
  for (int ii = 0; ii < 4; ii++) {
    int r = wid + ii * 8;                   // r&7 == wid
    const short* src = Kb + (size_t)(batch * LSEQ + t * 32 + r) * DIM + ((lane ^ wid) * 8);
    gld16(src, Klbuf + r * 512);
  }
}

__global__ __launch_bounds__(512, 2) void attn_kernel(
    const short* __restrict__ Qb, const short* __restrict__ Kb,
    const short* __restrict__ Vtb, float* __restrict__ out) {
  __shared__ short Kl[2][32 * 512];    // 64 KB dbuf
  __shared__ short P_lds[2][128][36];  // block-shared P, dbuf, 18.4 KB
  __shared__ float alpha_lds[2][8];
  __shared__ float dsum[128];
  int tid = threadIdx.x, lane = tid & 63, wid = tid >> 6;
  int l15 = lane & 15, lg = lane >> 4;
  int batch = blockIdx.x;
  f32x4 zero4 = {0.f, 0.f, 0.f, 0.f};
  short8 ones;
  #pragma unroll
  for (int i = 0; i < 8; i++) ones[i] = (short)0x3F80;

  for (int qpass = 0; qpass < 2; qpass++) {
    int qt = qpass ? (int)blockIdx.y : 15 - (int)blockIdx.y;  // long pass first
    int qb0 = qt * 128;
    int q0w = qb0 + wid * 16;
    int nt = qt * 4 + 4;

    stage_k(Kb, Kl[0], batch, 0, wid, lane);  // prologue prefetch

    const short* qrow = Qb + (size_t)(batch * LSEQ + q0w + l15) * DIM;
    short8 qf[16];
    #pragma unroll
    for (int kt = 0; kt < 16; kt++) qf[kt] = *(const short8*)(qrow + kt * 32 + lg * 8);

    f32x4 oacc[8][4];  // [q-tile][e4] for dims [wid*64, +64)
    #pragma unroll
    for (int i = 0; i < 8; i++)
      #pragma unroll
      for (int j = 0; j < 4; j++) oacc[i][j] = zero4;
    f32x4 dacc = zero4;
    float mrun = -1e30f;

    __syncthreads();  // drains prologue stage; fences LDS reuse across qpass

    for (int t = 0; t < nt; t++) {
      int cur = t & 1;
      if (t + 1 < nt)
        stage_k(Kb, Kl[cur ^ 1], batch, t + 1, wid, lane);

      // V slice loads: issue now, consume after barrier (latency under QK^T)
      short8 bv[4];
      const short* vt = Vtb + (size_t)(batch * 64 + t) * 16384;
      #pragma unroll
      for (int e4 = 0; e4 < 4; e4++)
        bv[e4] = *(const short8*)(vt + (wid * 64 + e4 * 16 + l15) * 32 + lg * 8);

      bool wave_active = (t * 32 <= q0w + 15);
      if (wave_active) {
        const short* Kc = Kl[cur];
        f32x4 sacc[2] = {zero4, zero4};
        __builtin_amdgcn_s_setprio(1);
        #pragma unroll
        for (int kt = 0; kt < 16; kt++) {
          #pragma unroll
          for (int c = 0; c < 2; c++) {
            int kr = c * 16 + l15;
            int j = kt * 4 + lg;
            short8 bk = *(const short8*)&Kc[kr * 512 + ((j ^ (kr & 7)) * 8)];
            sacc[c] = __builtin_amdgcn_mfma_f32_16x16x32_bf16(qf[kt], bk, sacc[c], 0, 0, 0);
          }
        }
        __builtin_amdgcn_s_setprio(0);
        // scores already in exp2 domain (SCALE*LOG2E folded into Qb)
        float s0[4], s1[4];
        float mx = -1e30f;
        bool diag = (t * 32 + 31 > q0w);
        #pragma unroll
        for (int r = 0; r < 4; r++) {
          s0[r] = sacc[0][r];
          s1[r] = sacc[1][r];
          if (diag) {
            int q = q0w + lg * 4 + r;
            if (t * 32 + l15 > q) s0[r] = -1e30f;
            if (t * 32 + 16 + l15 > q) s1[r] = -1e30f;
          }
          mx = fmaxf(mx, fmaxf(s0[r], s1[r]));
        }
        #pragma unroll
        for (int off = 1; off < 64; off <<= 1) mx = fmaxf(mx, __shfl_xor(mx, off, 64));
        float alpha_local = 1.f;
        if (mx > mrun + 11.5f) {  // defer-max, wave-uniform
          alpha_local = exp2f(mrun - mx);
          mrun = mx;
        }
        #pragma unroll
        for (int r = 0; r < 4; r++) {
          P_lds[cur][wid * 16 + lg * 4 + r][l15] = f2bs(exp2f(s0[r] - mrun));
          P_lds[cur][wid * 16 + lg * 4 + r][16 + l15] = f2bs(exp2f(s1[r] - mrun));
        }
        if (lane == 0) alpha_lds[cur][wid] = alpha_local;
        // denominator: own q-rows, wave-local RAW on P_lds (no barrier needed)
        if (alpha_local != 1.0f) {
          dacc[0] *= alpha_local; dacc[1] *= alpha_local;
          dacc[2] *= alpha_local; dacc[3] *= alpha_local;
        }
        short8 paw = *(const short8*)&P_lds[cur][wid * 16 + l15][lg * 8];
        dacc = __builtin_amdgcn_mfma_f32_16x16x32_bf16(paw, ones, dacc, 0, 0, 0);
      }
      __syncthreads();  // P publish + vmcnt drain (K prefetch)
      __builtin_amdgcn_s_setprio(1);
      #pragma unroll
      for (int qt8 = 0; qt8 < 8; qt8++) {
        if (t * 32 <= qb0 + qt8 * 16 + 15) {  // q-tile active (uniform)
          float a = alpha_lds[cur][qt8];
          short8 pa = *(const short8*)&P_lds[cur][qt8 * 16 + l15][lg * 8];
          if (a != 1.0f) {
            #pragma unroll
            for (int e4 = 0; e4 < 4; e4++) {
              oacc[qt8][e4][0] *= a; oacc[qt8][e4][1] *= a;
              oacc[qt8][e4][2] *= a; oacc[qt8][e4][3] *= a;
            }
          }
          #pragma unroll
          for (int e4 = 0; e4 < 4; e4++)
            oacc[qt8][e4] = __builtin_amdgcn_mfma_f32_16x16x32_bf16(pa, bv[e4], oacc[qt8][e4], 0, 0, 0);
        }
      }
      __builtin_amdgcn_s_setprio(0);
      // no second barrier: PV(t) reads P_lds[cur]/bv only; next tile's QK
      // reads Kl[cur^1] (drained above) and writes P_lds[cur^1].
    }
    // epilogue: broadcast denominators, then write wave's dim-slice
    if (l15 == 0) {
      #pragma unroll
      for (int r = 0; r < 4; r++) dsum[wid * 16 + lg * 4 + r] = dacc[r];
    }
    __syncthreads();
    #pragma unroll
    for (int qt8 = 0; qt8 < 8; qt8++) {
      #pragma unroll
      for (int r = 0; r < 4; r++) {
        float inv = 1.0f / dsum[qt8 * 16 + lg * 4 + r];
        int q = qb0 + qt8 * 16 + lg * 4 + r;
        #pragma unroll
        for (int e4 = 0; e4 < 4; e4++)
          out[((size_t)(batch * LSEQ + q)) * DIM + wid * 64 + e4 * 16 + l15] =
              oacc[qt8][e4][r] * inv;
      }
    }
    __syncthreads();  // dsum/P/K reuse safe before next qpass
  }
}

extern "C" void kernel_launch(void* const* d_in, const int* in_sizes, int n_in,
                              void* d_out, int out_size, void* d_ws, size_t ws_size,
                              hipStream_t stream) {
  const float* Ez = (const float*)d_in[0];
  const float* Wq = (const float*)d_in[1];
  const float* Wk = (const float*)d_in[2];
  const float* Wv = (const float*)d_in[3];
  const int* zp = (const int*)d_in[4];
  float* out = (float*)d_out;
  short* Qb = (short*)d_ws;
  short* Kb = Qb + (size_t)NB * LSEQ * DIM;
  short* Vtb = Kb + (size_t)NB * LSEQ * DIM;
  short* Wb = (short*)d_out;  // scratch: proj completes before attn writes out
  hipLaunchKernelGGL(wcvt_kernel, dim3(384), dim3(256), 0, stream,
                     Wq, Wk, Wv, zp, Wb);
  hipLaunchKernelGGL(proj_kernel, dim3(1024, 1, 3), dim3(512), 0, stream,
                     Ez, Wb, Qb, Kb, Vtb);
  hipLaunchKernelGGL(attn_kernel, dim3(32, 8), dim3(512), 0, stream,
                     Qb, Kb, Vtb, out);
}

// Round 9
// 457.074 us; speedup vs baseline: 1.2936x; 1.2936x over previous
//
#include <hip/hip_runtime.h>
#include <hip/hip_bf16.h>

// SelfAttention: out = softmax(causal((Ez Wq^T)(Ez Wk^T)^T / sqrt(512))) (Ez Wv^T)
// B=32, L=2048, DIM=512. f32 in/out; bf16 MFMA internally.
// ws: Qb (bf16, Q*SCALE*LOG2E), Kb (bf16), Vtb (bf16, [b][t][e][32] tile-contig,
// chunk-XOR pre-baked). Wb (bf16 [g][kt][n][32], swizzled) in d_out scratch.

typedef __attribute__((ext_vector_type(8))) short short8;
typedef __attribute__((ext_vector_type(4))) short short4v;
typedef __attribute__((ext_vector_type(4))) float f32x4;

#define DIM 512
#define LSEQ 2048
#define NB 32
#define SCALE 0.04419417382415922f
#define LOG2E 1.4426950408889634f

__device__ __forceinline__ short f2bs(float f) {
  __hip_bfloat16 h = __float2bfloat16(f);
  return __builtin_bit_cast(short, h);
}

__device__ __forceinline__ void gld16(const void* g, void* l) {
  __builtin_amdgcn_global_load_lds(
      (const unsigned int __attribute__((address_space(1)))*)g,
      (unsigned int __attribute__((address_space(3)))*)l, 16, 0, 0);
}

// ---- W[z] f32 -> bf16, layout [g][kt][n][32 d-chunk-swizzled] --------------
__global__ __launch_bounds__(256) void wcvt_kernel(
    const float* __restrict__ Wq, const float* __restrict__ Wk,
    const float* __restrict__ Wv, const int* __restrict__ zp,
    short* __restrict__ Wb) {
  int z = *zp;
  int i = blockIdx.x * 256 + threadIdx.x;
  int g = i >> 15;
  int off = (i & 32767) * 8;                   // flat [n][d], d fast
  int n = off >> 9, d0 = off & 511;
  int kt = d0 >> 5, c = d0 & 31;
  int sw = ((c >> 3) ^ ((n >> 1) & 3));
  const float* src = (g == 0 ? Wq : (g == 1 ? Wk : Wv)) + (size_t)z * DIM * DIM + off;
  float4 a = *(const float4*)src, b = *(const float4*)(src + 4);
  short8 v;
  v[0]=f2bs(a.x); v[1]=f2bs(a.y); v[2]=f2bs(a.z); v[3]=f2bs(a.w);
  v[4]=f2bs(b.x); v[5]=f2bs(b.y); v[6]=f2bs(b.z); v[7]=f2bs(b.w);
  *(short8*)&Wb[((size_t)(g * 16 + kt) * 512 + n) * 32 + sw * 8] = v;
}

// ---- projection GEMM: C[m][n] = sum_d Ez[m][d] * W[n][d] -------------------
__global__ __launch_bounds__(512, 4) void proj_kernel(
    const float* __restrict__ Ez, const short* __restrict__ Wb,
    short* __restrict__ Qb, short* __restrict__ Kb, short* __restrict__ Vtb) {
  int g = blockIdx.z;
  const short* W = Wb + (size_t)g * 16 * 512 * 32;
  __shared__ short As[2][64 * 32];
  __shared__ short Bs[2][512 * 32];
  int tid = threadIdx.x, lane = tid & 63, wid = tid >> 6;
  int l15 = lane & 15, lg = lane >> 4;
  int m0 = blockIdx.x * 64;
  int sw = (l15 >> 1) & 3;
  f32x4 zero4 = {0.f, 0.f, 0.f, 0.f};
  f32x4 acc[4][4];
  #pragma unroll
  for (int mi = 0; mi < 4; mi++)
    #pragma unroll
    for (int ni = 0; ni < 4; ni++) acc[mi][ni] = zero4;

  int arow = tid >> 3, aq = tid & 7;
  int aoff = arow * 32 + (((aq >> 1) ^ ((arow >> 1) & 3)) << 3) + (aq & 1) * 4;
  const float* aptr = Ez + (size_t)(m0 + arow) * DIM + aq * 4;

  {  // prologue: stage kt=0
    float4 a = *(const float4*)aptr;
    short4v av;
    av[0]=f2bs(a.x); av[1]=f2bs(a.y); av[2]=f2bs(a.z); av[3]=f2bs(a.w);
    *(short4v*)&As[0][aoff] = av;
    #pragma unroll
    for (int ii = 0; ii < 4; ii++) {
      int s = wid * 4 + ii;
      gld16(W + s * 512 + lane * 8, &Bs[0][s * 512]);
    }
  }
  __syncthreads();

  #pragma unroll 2
  for (int kt = 0; kt < 16; kt++) {
    int cur = kt & 1;
    float4 a;
    if (kt < 15) {
      a = *(const float4*)(aptr + (kt + 1) * 32);
      #pragma unroll
      for (int ii = 0; ii < 4; ii++) {
        int s = wid * 4 + ii;
        gld16(W + (size_t)(kt + 1) * 16384 + s * 512 + lane * 8, &Bs[cur ^ 1][s * 512]);
      }
    }
    short8 af[4], bf[4];
    #pragma unroll
    for (int mi = 0; mi < 4; mi++)
      af[mi] = *(const short8*)&As[cur][(mi * 16 + l15) * 32 + ((lg ^ sw) << 3)];
    #pragma unroll
    for (int ni = 0; ni < 4; ni++)
      bf[ni] = *(const short8*)&Bs[cur][(wid * 64 + ni * 16 + l15) * 32 + ((lg ^ sw) << 3)];
    __builtin_amdgcn_s_setprio(1);
    #pragma unroll
    for (int mi = 0; mi < 4; mi++)
      #pragma unroll
      for (int ni = 0; ni < 4; ni++)
        acc[mi][ni] = __builtin_amdgcn_mfma_f32_16x16x32_bf16(af[mi], bf[ni], acc[mi][ni], 0, 0, 0);
    __builtin_amdgcn_s_setprio(0);
    if (kt < 15) {
      short4v av;
      av[0]=f2bs(a.x); av[1]=f2bs(a.y); av[2]=f2bs(a.z); av[3]=f2bs(a.w);
      *(short4v*)&As[cur ^ 1][aoff] = av;
    }
    __syncthreads();
  }

  if (g == 2) {
    #pragma unroll
    for (int mi = 0; mi < 4; mi++) {
      int gm0 = m0 + mi * 16 + lg * 4;
      int b = gm0 >> 11, l0 = gm0 & (LSEQ - 1);
      int t = l0 >> 5, c0 = l0 & 31;
      #pragma unroll
      for (int ni = 0; ni < 4; ni++) {
        int e = wid * 64 + ni * 16 + l15;
        short4v v;
        v[0]=f2bs(acc[mi][ni][0]); v[1]=f2bs(acc[mi][ni][1]);
        v[2]=f2bs(acc[mi][ni][2]); v[3]=f2bs(acc[mi][ni][3]);
        size_t idx = ((size_t)(b * 64 + t) * 512 + e) * 32
                     + (((c0 >> 3) ^ ((e >> 1) & 3)) << 3) + (c0 & 7);
        *(short4v*)&Vtb[idx] = v;   // tile-contiguous V, read-swizzle pre-baked
      }
    }
  } else {
    short* dst = (g == 0 ? Qb : Kb);
    float sc = (g == 0 ? SCALE * LOG2E : 1.0f);  // Q pre-scaled, exp2 domain
    #pragma unroll
    for (int mi = 0; mi < 4; mi++) {
      int gm0 = m0 + mi * 16 + lg * 4;
      #pragma unroll
      for (int ni = 0; ni < 4; ni++) {
        int gn = wid * 64 + ni * 16 + l15;
        #pragma unroll
        for (int r = 0; r < 4; r++)
          dst[(size_t)(gm0 + r) * DIM + gn] = f2bs(acc[mi][ni][r] * sc);
      }
    }
  }
}

// ---- flash attention (causal) ----------------------------------------------
// Round-6 structure (best measured): 8 waves x 16 q-rows, per-wave softmax+P,
// K+V LDS double-buffered via global_load_lds, ONE barrier per tile.
// New: all swizzled LDS read addresses decomposed into lane-const bases +
// compile-time immediates (zero per-read VALU address math).
__device__ __forceinline__ void stage_kv(const short* __restrict__ Kb,
                                         const short* __restrict__ Vtb,
                                         short* Klbuf, short* Vlbuf,
                                         int batch, int t, int wid, int lane) {
  #pragma unroll
  for (int ii = 0; ii < 4; ii++) {          // K: rows wid, wid+8, wid+16, wid+24
    int r = wid + ii * 8;                   // r&7 == wid
    const short* src = Kb + (size_t)(batch * LSEQ + t * 32 + r) * DIM + ((lane ^ wid) * 8);
    gld16(src, Klbuf + r * 512);
  }
  const short* vt = Vtb + (size_t)(batch * 64 + t) * 16384;  // contiguous 32KB tile
  #pragma unroll
  for (int ii = 0; ii < 4; ii++) {
    int s = wid * 4 + ii;
    gld16(vt + s * 512 + lane * 8, Vlbuf + s * 512);
  }
}

__global__ __launch_bounds__(512, 2) void attn_kernel(
    const short* __restrict__ Qb, const short* __restrict__ Kb,
    const short* __restrict__ Vtb, float* __restrict__ out) {
  __shared__ short Kl[2][32 * 512];   // 64 KB dbuf
  __shared__ short Vl[2][512 * 32];   // 64 KB dbuf
  __shared__ short P_lds[8][16][36];  // per-wave P transpose, 9 KB
  int tid = threadIdx.x, lane = tid & 63, wid = tid >> 6;
  int l15 = lane & 15, lg = lane >> 4;
  int batch = blockIdx.x;
  f32x4 zero4 = {0.f, 0.f, 0.f, 0.f};
  short8 ones;
  #pragma unroll
  for (int i = 0; i < 8; i++) ones[i] = (short)0x3F80;

  // lane-const LDS offsets (shorts):
  // K swizzle: j^(kr&7) = 4*(kt^a)+(lg^b), a=(l15>>2)&1, b=l15&3
  int a0 = (l15 >> 2) & 1, b0 = l15 & 3;
  int kqE = l15 * 512 + 8 * (lg ^ b0) + 32 * a0;  // even-kt base (c=0; c=1 -> +8192)
  int kqO = l15 * 512 + 8 * (lg ^ b0) - 32 * a0;  // odd-kt base
  int voff = l15 * 32 + 8 * (lg ^ ((l15 >> 1) & 3));  // V base (+512*et)
  short* pw = &P_lds[wid][lg * 4][l15];               // P write base (+36*r, +16)
  const short* pr = &P_lds[wid][l15][lg * 8];         // P read (A-frag)

  for (int qpass = 0; qpass < 2; qpass++) {
    int qt = qpass ? (int)blockIdx.y : 15 - (int)blockIdx.y;  // long pass first
    int qb0 = qt * 128;
    int q0w = qb0 + wid * 16;
    int nt = qt * 4 + 4;

    stage_kv(Kb, Vtb, Kl[0], Vl[0], batch, 0, wid, lane);  // prologue prefetch

    const short* qrow = Qb + (size_t)(batch * LSEQ + q0w + l15) * DIM;
    short8 qf[16];  // Q rows in regs (SCALE*LOG2E pre-folded)
    #pragma unroll
    for (int kt = 0; kt < 16; kt++) qf[kt] = *(const short8*)(qrow + kt * 32 + lg * 8);

    f32x4 oacc[32];
    #pragma unroll
    for (int i = 0; i < 32; i++) oacc[i] = zero4;
    f32x4 dacc = zero4;   // per-row softmax denominator (via ones-MFMA)
    float mrun = -1e30f;  // joint running max (uniform across wave)

    __syncthreads();  // drains prologue stage (vmcnt) + syncs

    for (int t = 0; t < nt; t++) {
      int cur = t & 1;
      if (t + 1 < nt)
        stage_kv(Kb, Vtb, Kl[cur ^ 1], Vl[cur ^ 1], batch, t + 1, wid, lane);

      if (t * 32 <= q0w + 15) {  // wave-local causal skip
        const short* pE = Kl[cur] + kqE;
        const short* pO = Kl[cur] + kqO;
        f32x4 sacc[2] = {zero4, zero4};
        __builtin_amdgcn_s_setprio(1);
        #pragma unroll
        for (int kt = 0; kt < 16; kt += 2) {
          short8 k0 = *(const short8*)(pE + 32 * kt);
          short8 k1 = *(const short8*)(pE + 8192 + 32 * kt);
          sacc[0] = __builtin_amdgcn_mfma_f32_16x16x32_bf16(qf[kt], k0, sacc[0], 0, 0, 0);
          sacc[1] = __builtin_amdgcn_mfma_f32_16x16x32_bf16(qf[kt], k1, sacc[1], 0, 0, 0);
          short8 k2 = *(const short8*)(pO + 32 * (kt + 1));
          short8 k3 = *(const short8*)(pO + 8192 + 32 * (kt + 1));
          sacc[0] = __builtin_amdgcn_mfma_f32_16x16x32_bf16(qf[kt + 1], k2, sacc[0], 0, 0, 0);
          sacc[1] = __builtin_amdgcn_mfma_f32_16x16x32_bf16(qf[kt + 1], k3, sacc[1], 0, 0, 0);
        }
        __builtin_amdgcn_s_setprio(0);
        // softmax (exp2 domain; scores pre-scaled). Joint per-wave max.
        float s0[4], s1[4];
        if (t * 32 + 31 > q0w) {  // diagonal tiles only: apply causal mask
          #pragma unroll
          for (int r = 0; r < 4; r++) {
            int q = q0w + lg * 4 + r;
            s0[r] = (t * 32 + l15 > q) ? -1e30f : sacc[0][r];
            s1[r] = (t * 32 + 16 + l15 > q) ? -1e30f : sacc[1][r];
          }
        } else {
          #pragma unroll
          for (int r = 0; r < 4; r++) { s0[r] = sacc[0][r]; s1[r] = sacc[1][r]; }
        }
        float mx = fmaxf(fmaxf(fmaxf(s0[0], s0[1]), fmaxf(s0[2], s0[3])),
                         fmaxf(fmaxf(s1[0], s1[1]), fmaxf(s1[2], s1[3])));
        #pragma unroll
        for (int off = 1; off < 64; off <<= 1) mx = fmaxf(mx, __shfl_xor(mx, off, 64));
        if (mx > mrun + 11.5f) {  // defer-max, wave-uniform
          float alpha = exp2f(mrun - mx);
          mrun = mx;
          dacc[0] *= alpha; dacc[1] *= alpha; dacc[2] *= alpha; dacc[3] *= alpha;
          #pragma unroll
          for (int et = 0; et < 32; et++) {
            oacc[et][0] *= alpha; oacc[et][1] *= alpha;
            oacc[et][2] *= alpha; oacc[et][3] *= alpha;
          }
        }
        #pragma unroll
        for (int r = 0; r < 4; r++) {
          pw[r * 36] = f2bs(exp2f(s0[r] - mrun));
          pw[r * 36 + 16] = f2bs(exp2f(s1[r] - mrun));
        }
        short8 pa = *(const short8*)pr;  // wave-local RAW
        const short* vb = Vl[cur] + voff;
        __builtin_amdgcn_s_setprio(1);
        dacc = __builtin_amdgcn_mfma_f32_16x16x32_bf16(pa, ones, dacc, 0, 0, 0);
        #pragma unroll
        for (int et = 0; et < 32; et++) {
          short8 bv = *(const short8*)(vb + et * 512);
          oacc[et] = __builtin_amdgcn_mfma_f32_16x16x32_bf16(pa, bv, oacc[et], 0, 0, 0);
        }
        __builtin_amdgcn_s_setprio(0);
      }
      __syncthreads();  // drains prefetch (vmcnt) + releases buffers
    }
    // epilogue: per-wave divide by denominator, write 16 q-rows x 512 dims
    float inv[4];
    #pragma unroll
    for (int r = 0; r < 4; r++) inv[r] = 1.0f / dacc[r];
    #pragma unroll
    for (int et = 0; et < 32; et++)
      #pragma unroll
      for (int r = 0; r < 4; r++) {
        int q = q0w + lg * 4 + r;
        out[((size_t)(batch * LSEQ + q)) * DIM + et * 16 + l15] = oacc[et][r] * inv[r];
      }
  }
}

extern "C" void kernel_launch(void* const* d_in, const int* in_sizes, int n_in,
                              void* d_out, int out_size, void* d_ws, size_t ws_size,
                              hipStream_t stream) {
  const float* Ez = (const float*)d_in[0];
  const float* Wq = (const float*)d_in[1];
  const float* Wk = (const float*)d_in[2];
  const float* Wv = (const float*)d_in[3];
  const int* zp = (const int*)d_in[4];
  float* out = (float*)d_out;
  short* Qb = (short*)d_ws;
  short* Kb = Qb + (size_t)NB * LSEQ * DIM;
  short* Vtb = Kb + (size_t)NB * LSEQ * DIM;
  short* Wb = (short*)d_out;  // scratch: proj completes before attn writes out
  hipLaunchKernelGGL(wcvt_kernel, dim3(384), dim3(256), 0, stream,
                     Wq, Wk, Wv, zp, Wb);
  hipLaunchKernelGGL(proj_kernel, dim3(1024, 1, 3), dim3(512), 0, stream,
                     Ez, Wb, Qb, Kb, Vtb);
  hipLaunchKernelGGL(attn_kernel, dim3(32, 8), dim3(512), 0, stream,
                     Qb, Kb, Vtb, out);
}

// Round 12
// 436.452 us; speedup vs baseline: 1.3548x; 1.0472x over previous
//
#include <hip/hip_runtime.h>
#include <hip/hip_bf16.h>

// SelfAttention: out = softmax(causal((Ez Wq^T)(Ez Wk^T)^T / sqrt(512))) (Ez Wv^T)
// B=32, L=2048, DIM=512. f32 in/out; bf16 MFMA internally.
// ws: Qb (bf16, Q*SCALE*LOG2E), Kb (bf16), Vtb (bf16, [b][t][e][32] tile-contig,
// chunk-XOR pre-baked). Wb (bf16 [g][kt][n][32], swizzled) in d_out scratch.
// R12 = proven R9 kernel + (1) P_lds stride 36->40 (16B-aligned, bank-clean),
// (2) lazy softmax max (__any-triggered shfl reduce).

typedef __attribute__((ext_vector_type(8))) short short8;
typedef __attribute__((ext_vector_type(4))) short short4v;
typedef __attribute__((ext_vector_type(4))) float f32x4;

#define DIM 512
#define LSEQ 2048
#define NB 32
#define SCALE 0.04419417382415922f
#define LOG2E 1.4426950408889634f

__device__ __forceinline__ short f2bs(float f) {
  __hip_bfloat16 h = __float2bfloat16(f);
  return __builtin_bit_cast(short, h);
}

__device__ __forceinline__ void gld16(const void* g, void* l) {
  __builtin_amdgcn_global_load_lds(
      (const unsigned int __attribute__((address_space(1)))*)g,
      (unsigned int __attribute__((address_space(3)))*)l, 16, 0, 0);
}

// ---- W[z] f32 -> bf16, layout [g][kt][n][32 d-chunk-swizzled] --------------
__global__ __launch_bounds__(256) void wcvt_kernel(
    const float* __restrict__ Wq, const float* __restrict__ Wk,
    const float* __restrict__ Wv, const int* __restrict__ zp,
    short* __restrict__ Wb) {
  int z = *zp;
  int i = blockIdx.x * 256 + threadIdx.x;
  int g = i >> 15;
  int off = (i & 32767) * 8;                   // flat [n][d], d fast
  int n = off >> 9, d0 = off & 511;
  int kt = d0 >> 5, c = d0 & 31;
  int sw = ((c >> 3) ^ ((n >> 1) & 3));
  const float* src = (g == 0 ? Wq : (g == 1 ? Wk : Wv)) + (size_t)z * DIM * DIM + off;
  float4 a = *(const float4*)src, b = *(const float4*)(src + 4);
  short8 v;
  v[0]=f2bs(a.x); v[1]=f2bs(a.y); v[2]=f2bs(a.z); v[3]=f2bs(a.w);
  v[4]=f2bs(b.x); v[5]=f2bs(b.y); v[6]=f2bs(b.z); v[7]=f2bs(b.w);
  *(short8*)&Wb[((size_t)(g * 16 + kt) * 512 + n) * 32 + sw * 8] = v;
}

// ---- projection GEMM: C[m][n] = sum_d Ez[m][d] * W[n][d] -------------------
__global__ __launch_bounds__(512, 4) void proj_kernel(
    const float* __restrict__ Ez, const short* __restrict__ Wb,
    short* __restrict__ Qb, short* __restrict__ Kb, short* __restrict__ Vtb) {
  int g = blockIdx.z;
  const short* W = Wb + (size_t)g * 16 * 512 * 32;
  __shared__ short As[2][64 * 32];
  __shared__ short Bs[2][512 * 32];
  int tid = threadIdx.x, lane = tid & 63, wid = tid >> 6;
  int l15 = lane & 15, lg = lane >> 4;
  int m0 = blockIdx.x * 64;
  int sw = (l15 >> 1) & 3;
  f32x4 zero4 = {0.f, 0.f, 0.f, 0.f};
  f32x4 acc[4][4];
  #pragma unroll
  for (int mi = 0; mi < 4; mi++)
    #pragma unroll
    for (int ni = 0; ni < 4; ni++) acc[mi][ni] = zero4;

  int arow = tid >> 3, aq = tid & 7;
  int aoff = arow * 32 + (((aq >> 1) ^ ((arow >> 1) & 3)) << 3) + (aq & 1) * 4;
  const float* aptr = Ez + (size_t)(m0 + arow) * DIM + aq * 4;

  {  // prologue: stage kt=0
    float4 a = *(const float4*)aptr;
    short4v av;
    av[0]=f2bs(a.x); av[1]=f2bs(a.y); av[2]=f2bs(a.z); av[3]=f2bs(a.w);
    *(short4v*)&As[0][aoff] = av;
    #pragma unroll
    for (int ii = 0; ii < 4; ii++) {
      int s = wid * 4 + ii;
      gld16(W + s * 512 + lane * 8, &Bs[0][s * 512]);
    }
  }
  __syncthreads();

  #pragma unroll 2
  for (int kt = 0; kt < 16; kt++) {
    int cur = kt & 1;
    float4 a;
    if (kt < 15) {
      a = *(const float4*)(aptr + (kt + 1) * 32);
      #pragma unroll
      for (int ii = 0; ii < 4; ii++) {
        int s = wid * 4 + ii;
        gld16(W + (size_t)(kt + 1) * 16384 + s * 512 + lane * 8, &Bs[cur ^ 1][s * 512]);
      }
    }
    short8 af[4], bf[4];
    #pragma unroll
    for (int mi = 0; mi < 4; mi++)
      af[mi] = *(const short8*)&As[cur][(mi * 16 + l15) * 32 + ((lg ^ sw) << 3)];
    #pragma unroll
    for (int ni = 0; ni < 4; ni++)
      bf[ni] = *(const short8*)&Bs[cur][(wid * 64 + ni * 16 + l15) * 32 + ((lg ^ sw) << 3)];
    __builtin_amdgcn_s_setprio(1);
    #pragma unroll
    for (int mi = 0; mi < 4; mi++)
      #pragma unroll
      for (int ni = 0; ni < 4; ni++)
        acc[mi][ni] = __builtin_amdgcn_mfma_f32_16x16x32_bf16(af[mi], bf[ni], acc[mi][ni], 0, 0, 0);
    __builtin_amdgcn_s_setprio(0);
    if (kt < 15) {
      short4v av;
      av[0]=f2bs(a.x); av[1]=f2bs(a.y); av[2]=f2bs(a.z); av[3]=f2bs(a.w);
      *(short4v*)&As[cur ^ 1][aoff] = av;
    }
    __syncthreads();
  }

  if (g == 2) {
    #pragma unroll
    for (int mi = 0; mi < 4; mi++) {
      int gm0 = m0 + mi * 16 + lg * 4;
      int b = gm0 >> 11, l0 = gm0 & (LSEQ - 1);
      int t = l0 >> 5, c0 = l0 & 31;
      #pragma unroll
      for (int ni = 0; ni < 4; ni++) {
        int e = wid * 64 + ni * 16 + l15;
        short4v v;
        v[0]=f2bs(acc[mi][ni][0]); v[1]=f2bs(acc[mi][ni][1]);
        v[2]=f2bs(acc[mi][ni][2]); v[3]=f2bs(acc[mi][ni][3]);
        size_t idx = ((size_t)(b * 64 + t) * 512 + e) * 32
                     + (((c0 >> 3) ^ ((e >> 1) & 3)) << 3) + (c0 & 7);
        *(short4v*)&Vtb[idx] = v;   // tile-contiguous V, read-swizzle pre-baked
      }
    }
  } else {
    short* dst = (g == 0 ? Qb : Kb);
    float sc = (g == 0 ? SCALE * LOG2E : 1.0f);  // Q pre-scaled, exp2 domain
    #pragma unroll
    for (int mi = 0; mi < 4; mi++) {
      int gm0 = m0 + mi * 16 + lg * 4;
      #pragma unroll
      for (int ni = 0; ni < 4; ni++) {
        int gn = wid * 64 + ni * 16 + l15;
        #pragma unroll
        for (int r = 0; r < 4; r++)
          dst[(size_t)(gm0 + r) * DIM + gn] = f2bs(acc[mi][ni][r] * sc);
      }
    }
  }
}

// ---- flash attention (causal) ----------------------------------------------
// R9 structure: 8 waves x 16 q-rows, per-wave softmax+P, K+V LDS dbuf via
// global_load_lds, ONE barrier per tile, lane-const LDS addressing.
__device__ __forceinline__ void stage_kv(const short* __restrict__ Kb,
                                         const short* __restrict__ Vtb,
                                         short* Klbuf, short* Vlbuf,
                                         int batch, int t, int wid, int lane) {
  #pragma unroll
  for (int ii = 0; ii < 4; ii++) {          // K: rows wid, wid+8, wid+16, wid+24
    int r = wid + ii * 8;                   // r&7 == wid
    const short* src = Kb + (size_t)(batch * LSEQ + t * 32 + r) * DIM + ((lane ^ wid) * 8);
    gld16(src, Klbuf + r * 512);
  }
  const short* vt = Vtb + (size_t)(batch * 64 + t) * 16384;  // contiguous 32KB tile
  #pragma unroll
  for (int ii = 0; ii < 4; ii++) {
    int s = wid * 4 + ii;
    gld16(vt + s * 512 + lane * 8, Vlbuf + s * 512);
  }
}

__global__ __launch_bounds__(512, 2) void attn_kernel(
    const short* __restrict__ Qb, const short* __restrict__ Kb,
    const short* __restrict__ Vtb, float* __restrict__ out) {
  __shared__ short Kl[2][32 * 512];   // 64 KB dbuf
  __shared__ short Vl[2][512 * 32];   // 64 KB dbuf
  __shared__ short P_lds[8][16][40];  // per-wave P transpose; 40-stride: 16B-aligned
  int tid = threadIdx.x, lane = tid & 63, wid = tid >> 6;
  int l15 = lane & 15, lg = lane >> 4;
  int batch = blockIdx.x;
  f32x4 zero4 = {0.f, 0.f, 0.f, 0.f};
  short8 ones;
  #pragma unroll
  for (int i = 0; i < 8; i++) ones[i] = (short)0x3F80;

  // lane-const LDS offsets (shorts):
  // K swizzle: j^(kr&7) = 4*(kt^a0)+(lg^b0), a0=(l15>>2)&1, b0=l15&3
  int a0 = (l15 >> 2) & 1, b0 = l15 & 3;
  int kqE = l15 * 512 + 8 * (lg ^ b0) + 32 * a0;  // even-kt base (+8192 for c=1)
  int kqO = l15 * 512 + 8 * (lg ^ b0) - 32 * a0;  // odd-kt base
  int voff = l15 * 32 + 8 * (lg ^ ((l15 >> 1) & 3));  // V base (+512*et)
  short* pw = &P_lds[wid][lg * 4][l15];               // P write (+40*r, +16*c)
  const short* pr = &P_lds[wid][l15][lg * 8];         // P read (A-frag, aligned)

  for (int qpass = 0; qpass < 2; qpass++) {
    int qt = qpass ? (int)blockIdx.y : 15 - (int)blockIdx.y;  // long pass first
    int qb0 = qt * 128;
    int q0w = qb0 + wid * 16;
    int nt = qt * 4 + 4;

    stage_kv(Kb, Vtb, Kl[0], Vl[0], batch, 0, wid, lane);  // prologue prefetch

    const short* qrow = Qb + (size_t)(batch * LSEQ + q0w + l15) * DIM;
    short8 qf[16];  // Q rows in regs (SCALE*LOG2E pre-folded)
    #pragma unroll
    for (int kt = 0; kt < 16; kt++) qf[kt] = *(const short8*)(qrow + kt * 32 + lg * 8);

    f32x4 oacc[32];
    #pragma unroll
    for (int i = 0; i < 32; i++) oacc[i] = zero4;
    f32x4 dacc = zero4;   // per-row softmax denominator (via ones-MFMA)
    float mrun = -1e30f;  // wave-uniform running max (exp2 domain)

    __syncthreads();  // drains prologue stage (vmcnt) + syncs

    for (int t = 0; t < nt; t++) {
      int cur = t & 1;
      if (t + 1 < nt)
        stage_kv(Kb, Vtb, Kl[cur ^ 1], Vl[cur ^ 1], batch, t + 1, wid, lane);

      if (t * 32 <= q0w + 15) {  // wave-local causal skip
        const short* pE = Kl[cur] + kqE;
        const short* pO = Kl[cur] + kqO;
        f32x4 sacc[2] = {zero4, zero4};
        __builtin_amdgcn_s_setprio(1);
        #pragma unroll
        for (int kt = 0; kt < 16; kt += 2) {
          short8 k0 = *(const short8*)(pE + 32 * kt);
          short8 k1 = *(const short8*)(pE + 8192 + 32 * kt);
          sacc[0] = __builtin_amdgcn_mfma_f32_16x16x32_bf16(qf[kt], k0, sacc[0], 0, 0, 0);
          sacc[1] = __builtin_amdgcn_mfma_f32_16x16x32_bf16(qf[kt], k1, sacc[1], 0, 0, 0);
          short8 k2 = *(const short8*)(pO + 32 * (kt + 1));
          short8 k3 = *(const short8*)(pO + 8192 + 32 * (kt + 1));
          sacc[0] = __builtin_amdgcn_mfma_f32_16x16x32_bf16(qf[kt + 1], k2, sacc[0], 0, 0, 0);
          sacc[1] = __builtin_amdgcn_mfma_f32_16x16x32_bf16(qf[kt + 1], k3, sacc[1], 0, 0, 0);
        }
        __builtin_amdgcn_s_setprio(0);
        // softmax (exp2 domain; scores pre-scaled). Lazy wave max.
        float s0[4], s1[4];
        if (t * 32 + 31 > q0w) {  // diagonal tiles only: apply causal mask
          #pragma unroll
          for (int r = 0; r < 4; r++) {
            int q = q0w + lg * 4 + r;
            s0[r] = (t * 32 + l15 > q) ? -1e30f : sacc[0][r];
            s1[r] = (t * 32 + 16 + l15 > q) ? -1e30f : sacc[1][r];
          }
        } else {
          #pragma unroll
          for (int r = 0; r < 4; r++) { s0[r] = sacc[0][r]; s1[r] = sacc[1][r]; }
        }
        float lm = fmaxf(fmaxf(fmaxf(s0[0], s0[1]), fmaxf(s0[2], s0[3])),
                         fmaxf(fmaxf(s1[0], s1[1]), fmaxf(s1[2], s1[3])));
        if (__any(lm > mrun + 11.5f)) {  // rare: raise the wave max
          float mx = lm;
          #pragma unroll
          for (int off = 1; off < 64; off <<= 1) mx = fmaxf(mx, __shfl_xor(mx, off, 64));
          float alpha = exp2f(mrun - mx);
          mrun = mx;
          dacc[0] *= alpha; dacc[1] *= alpha; dacc[2] *= alpha; dacc[3] *= alpha;
          #pragma unroll
          for (int et = 0; et < 32; et++) {
            oacc[et][0] *= alpha; oacc[et][1] *= alpha;
            oacc[et][2] *= alpha; oacc[et][3] *= alpha;
          }
        }
        #pragma unroll
        for (int r = 0; r < 4; r++) {
          pw[r * 40] = f2bs(exp2f(s0[r] - mrun));
          pw[r * 40 + 16] = f2bs(exp2f(s1[r] - mrun));
        }
        short8 pa = *(const short8*)pr;  // wave-local RAW
        const short* vb = Vl[cur] + voff;
        __builtin_amdgcn_s_setprio(1);
        dacc = __builtin_amdgcn_mfma_f32_16x16x32_bf16(pa, ones, dacc, 0, 0, 0);
        #pragma unroll
        for (int et = 0; et < 32; et++) {
          short8 bv = *(const short8*)(vb + et * 512);
          oacc[et] = __builtin_amdgcn_mfma_f32_16x16x32_bf16(pa, bv, oacc[et], 0, 0, 0);
        }
        __builtin_amdgcn_s_setprio(0);
      }
      __syncthreads();  // drains prefetch (vmcnt) + releases buffers
    }
    // epilogue: per-wave divide by denominator, write 16 q-rows x 512 dims
    float inv[4];
    #pragma unroll
    for (int r = 0; r < 4; r++) inv[r] = 1.0f / dacc[r];
    #pragma unroll
    for (int et = 0; et < 32; et++)
      #pragma unroll
      for (int r = 0; r < 4; r++) {
        int q = q0w + lg * 4 + r;
        out[((size_t)(batch * LSEQ + q)) * DIM + et * 16 + l15] = oacc[et][r] * inv[r];
      }
  }
}

extern "C" void kernel_launch(void* const* d_in, const int* in_sizes, int n_in,
                              void* d_out, int out_size, void* d_ws, size_t ws_size,
                              hipStream_t stream) {
  const float* Ez = (const float*)d_in[0];
  const float* Wq = (const float*)d_in[1];
  const float* Wk = (const float*)d_in[2];
  const float* Wv = (const float*)d_in[3];
  const int* zp = (const int*)d_in[4];
  float* out = (float*)d_out;
  short* Qb = (short*)d_ws;
  short* Kb = Qb + (size_t)NB * LSEQ * DIM;
  short* Vtb = Kb + (size_t)NB * LSEQ * DIM;
  short* Wb = (short*)d_out;  // scratch: proj completes before attn writes out
  hipLaunchKernelGGL(wcvt_kernel, dim3(384), dim3(256), 0, stream,
                     Wq, Wk, Wv, zp, Wb);
  hipLaunchKernelGGL(proj_kernel, dim3(1024, 1, 3), dim3(512), 0, stream,
                     Ez, Wb, Qb, Kb, Vtb);
  hipLaunchKernelGGL(attn_kernel, dim3(32, 8), dim3(512), 0, stream,
                     Qb, Kb, Vtb, out);
}